// Round 4
// baseline (14698.357 us; speedup 1.0000x reference)
//
#include <hip/hip_runtime.h>
#include <math.h>

#define BATCH 128
#define SLEN  8000
#define HID   64
#define EPW   4                    // batch elements per wave
#define NBLK  (BATCH / EPW)        // 32 blocks
#define CHUNK 32                   // steps per fc flush; 8000 = 250 * 32
#define NCHUNK (SLEN / CHUNK)      // 250
#define ROWSTRIDE 68               // floats; 272 B rows, 16B-aligned

typedef float v2f __attribute__((ext_vector_type(2)));

__device__ __forceinline__ float fast_exp2(float x) { return __builtin_amdgcn_exp2f(x); }
__device__ __forceinline__ float fast_rcp(float x)  { return __builtin_amdgcn_rcpf(x); }

__device__ __forceinline__ float bcast_lane(float v, int lane) {
    return __int_as_float(__builtin_amdgcn_readlane(__float_as_int(v), lane));
}

// tanh(x) = sign(x) * (e - 1)/(e + 1), e = 2^(2|x|*log2 e)
__device__ __forceinline__ float tanh_fast(float x) {
    float ax = fabsf(x);
    float z  = fminf(ax * 2.8853900817779268f, 30.0f);
    float e  = fast_exp2(z);
    float r  = (e - 1.0f) * fast_rcp(e + 1.0f);
    return x < 0.0f ? -r : r;
}

__device__ __forceinline__ float sigmoid_fast(float x) {
    float z = fminf(fmaxf(-x * 1.4426950408889634f, -60.0f), 60.0f);
    float e = fast_exp2(z);
    return fast_rcp(1.0f + e);
}

__global__ __launch_bounds__(64) void rnn_pk4_kernel(
    const float* __restrict__ x,      // [B, S]
    const float* __restrict__ W_ih,   // [H, 1]
    const float* __restrict__ b_ih,   // [H]
    const float* __restrict__ W_hh,   // [H, H]
    const float* __restrict__ b_hh,   // [H]
    const float* __restrict__ fc_w,   // [2, H]
    const float* __restrict__ fc_b,   // [2]
    float* __restrict__ out)          // [B]
{
    // Per-element h history. Row r holds POST-update h_{c*32+r+1}; row 31 of the
    // previous chunk (still resident) provides h_t for step r=0.
    __shared__ float hbuf[EPW][CHUNK * ROWSTRIDE];

    const int lane = threadIdx.x;               // == hidden index i
    const int bb   = blockIdx.x;                // elements 4*bb .. 4*bb+3

    // Lane i holds W_hh row i as 32 packed float2 — shared by all 4 elements.
    v2f W2[32];
    #pragma unroll
    for (int q = 0; q < 16; ++q) {
        float4 t = ((const float4*)(W_hh + lane * HID))[q];
        W2[2*q+0] = (v2f){t.x, t.y};
        W2[2*q+1] = (v2f){t.z, t.w};
    }
    const float wih  = W_ih[lane];
    const float bias = b_ih[lane] + b_hh[lane];
    const float fcb0 = fc_b[0], fcb1 = fc_b[1];

    const float* xr[EPW];
    float h[EPW], xnext[EPW], xcur[EPW];
    #pragma unroll
    for (int e = 0; e < EPW; ++e) {
        xr[e] = x + (size_t)(EPW * bb + e) * SLEN;
        h[e]  = 0.0f;
        xnext[e] = xr[e][lane & 31];            // chunk 0's x (lanes 0-31 hold valid)
        hbuf[e][(CHUNK - 1) * ROWSTRIDE + lane] = 0.0f;   // seed h_0
    }

    float numA = 0.f, denA = 0.f;   // element (lane>>5)     : 0 or 1
    float numB = 0.f, denB = 0.f;   // element 2+(lane>>5)   : 2 or 3

    #pragma unroll 1
    for (int c = 0; c < NCHUNK; ++c) {
        #pragma unroll
        for (int e = 0; e < EPW; ++e) xcur[e] = xnext[e];
        const int nb = (c + 1 < NCHUNK) ? (c + 1) * CHUNK : 0;
        #pragma unroll
        for (int e = 0; e < EPW; ++e) xnext[e] = xr[e][nb + (lane & 31)];

        #pragma unroll 2
        for (int r = 0; r < CHUNK; ++r) {
            const int pr = (r + CHUNK - 1) & (CHUNK - 1);   // row holding h_t
            float xv[EPW];
            const float4* rowp[EPW];
            v2f acc[EPW][4];
            #pragma unroll
            for (int e = 0; e < EPW; ++e) {
                xv[e]   = bcast_lane(xcur[e], r);
                rowp[e] = (const float4*)(&hbuf[e][pr * ROWSTRIDE]);
                acc[e][0] = (v2f){fmaf(wih, xv[e], bias), 0.f};
                acc[e][1] = (v2f){0.f, 0.f};
                acc[e][2] = (v2f){0.f, 0.f};
                acc[e][3] = (v2f){0.f, 0.f};
            }
            // Round-robin by element: in-order DS FIFO pipelines the 4 chains.
            #pragma unroll
            for (int q = 0; q < 16; ++q) {
                #pragma unroll
                for (int e = 0; e < EPW; ++e) {
                    float4 ha = rowp[e][q];     // same-address broadcast, conflict-free
                    acc[e][(2*q)   & 3] = __builtin_elementwise_fma(
                        W2[2*q+0], (v2f){ha.x, ha.y}, acc[e][(2*q)   & 3]);
                    acc[e][(2*q+1) & 3] = __builtin_elementwise_fma(
                        W2[2*q+1], (v2f){ha.z, ha.w}, acc[e][(2*q+1) & 3]);
                }
            }
            #pragma unroll
            for (int e = 0; e < EPW; ++e) {
                v2f t0 = acc[e][0] + acc[e][1];
                v2f t1 = acc[e][2] + acc[e][3];
                v2f t2 = t0 + t1;
                h[e] = tanh_fast(t2.x + t2.y);
                hbuf[e][r * ROWSTRIDE + lane] = h[e];   // publish h_{t+1}
            }
        }

        // fc head flush: 128 rows (4 elem x 32 steps), 2 rows per lane.
        // k=0 -> element (lane>>5), k=1 -> element 2+(lane>>5); row = lane&31.
        {
            const int half = lane >> 5;
            const int rr   = lane & 31;
            const float4* rp0 = (const float4*)(&hbuf[half][rr * ROWSTRIDE]);
            const float4* rp1 = (const float4*)(&hbuf[2 + half][rr * ROWSTRIDE]);
            float d00 = 0.f, d01 = 0.f, d10 = 0.f, d11 = 0.f;
            #pragma unroll
            for (int q = 0; q < 16; ++q) {
                float4 f0 = ((const float4*)fc_w)[q];          // uniform -> s_load
                float4 f1 = ((const float4*)(fc_w + HID))[q];
                float4 a0 = rp0[q];
                float4 a1 = rp1[q];
                d00 += a0.x*f0.x + a0.y*f0.y + a0.z*f0.z + a0.w*f0.w;
                d01 += a0.x*f1.x + a0.y*f1.y + a0.z*f1.z + a0.w*f1.w;
                d10 += a1.x*f0.x + a1.y*f0.y + a1.z*f0.z + a1.w*f0.w;
                d11 += a1.x*f1.x + a1.y*f1.y + a1.z*f1.z + a1.w*f1.w;
            }
            float sel0 = sigmoid_fast(d00 + fcb0);
            float sco0 = sigmoid_fast(d01 + fcb1);
            float sel1 = sigmoid_fast(d10 + fcb0);
            float sco1 = sigmoid_fast(d11 + fcb1);
            numA = fmaf(sco0, sel0, numA);  denA += sel0;
            numB = fmaf(sco1, sel1, numB);  denB += sel1;
        }
        // next chunk's writes follow fc reads in program order; in-order DS => safe
    }

    // Reduce within each 32-lane half (elements are per-half).
    #pragma unroll
    for (int off = 16; off > 0; off >>= 1) {
        numA += __shfl_down(numA, off, 32);
        denA += __shfl_down(denA, off, 32);
        numB += __shfl_down(numB, off, 32);
        denB += __shfl_down(denB, off, 32);
    }
    if (lane == 0) {
        out[EPW * bb + 0] = numA / denA;
        out[EPW * bb + 2] = numB / denB;
    } else if (lane == 32) {
        out[EPW * bb + 1] = numA / denA;
        out[EPW * bb + 3] = numB / denB;
    }
}

extern "C" void kernel_launch(void* const* d_in, const int* in_sizes, int n_in,
                              void* d_out, int out_size, void* d_ws, size_t ws_size,
                              hipStream_t stream) {
    const float* x    = (const float*)d_in[0];
    const float* W_ih = (const float*)d_in[1];
    const float* b_ih = (const float*)d_in[2];
    const float* W_hh = (const float*)d_in[3];
    const float* b_hh = (const float*)d_in[4];
    const float* fc_w = (const float*)d_in[5];
    const float* fc_b = (const float*)d_in[6];
    float* out = (float*)d_out;

    rnn_pk4_kernel<<<NBLK, 64, 0, stream>>>(x, W_ih, b_ih, W_hh, b_hh,
                                            fc_w, fc_b, out);
}

// Round 5
// 2249.837 us; speedup vs baseline: 6.5331x; 6.5331x over previous
//
#include <hip/hip_runtime.h>
#include <math.h>

#define BATCH 128
#define SLEN  8000
#define HID   64
#define CHUNK 64                  // steps per fc flush; 8000 = 125 * 64
#define NCHUNK (SLEN / CHUNK)     // 125
#define ROWSTRIDE 68              // floats; 272 B rows, 16B-aligned

typedef _Float16 h2 __attribute__((ext_vector_type(2)));

__device__ __forceinline__ float fast_exp2(float x) { return __builtin_amdgcn_exp2f(x); }
__device__ __forceinline__ float fast_rcp(float x)  { return __builtin_amdgcn_rcpf(x); }

__device__ __forceinline__ float bcast_lane(float v, int lane) {
    return __int_as_float(__builtin_amdgcn_readlane(__float_as_int(v), lane));
}
__device__ __forceinline__ int h2_as_int(h2 v) {
    union { h2 h; int i; } u; u.h = v; return u.i;
}
__device__ __forceinline__ h2 int_as_h2(int v) {
    union { h2 h; int i; } u; u.i = v; return u.h;
}

// tanh(x) = sign(x) * (e - 1)/(e + 1), e = 2^(2|x|*log2 e)   (fp32 throughout)
__device__ __forceinline__ float tanh_fast(float x) {
    float ax = fabsf(x);
    float z  = fminf(ax * 2.8853900817779268f, 30.0f);
    float e  = fast_exp2(z);
    float r  = (e - 1.0f) * fast_rcp(e + 1.0f);
    return x < 0.0f ? -r : r;
}

__device__ __forceinline__ float sigmoid_fast(float x) {
    float z = fminf(fmaxf(-x * 1.4426950408889634f, -60.0f), 60.0f);
    float e = fast_exp2(z);
    return fast_rcp(1.0f + e);
}

__global__ __launch_bounds__(64) void rnn_dot2_kernel(
    const float* __restrict__ x,      // [B, S]
    const float* __restrict__ W_ih,   // [H, 1]
    const float* __restrict__ b_ih,   // [H]
    const float* __restrict__ W_hh,   // [H, H]
    const float* __restrict__ b_hh,   // [H]
    const float* __restrict__ fc_w,   // [2, H]
    const float* __restrict__ fc_b,   // [2]
    float* __restrict__ out)          // [B]
{
    __shared__ float hbuf[CHUNK * ROWSTRIDE];   // fp32 h history for the fc head

    const int lane = threadIdx.x;               // == hidden index i
    const int b    = blockIdx.x;
    const float* xrow = x + (size_t)b * SLEN;

    // Lane i holds W_hh row i packed to half2 (RNE converts): 32 VGPRs.
    h2 W16[32];
    #pragma unroll
    for (int q = 0; q < 16; ++q) {
        float4 t = ((const float4*)(W_hh + lane * HID))[q];
        h2 p0; p0.x = (_Float16)t.x; p0.y = (_Float16)t.y;
        h2 p1; p1.x = (_Float16)t.z; p1.y = (_Float16)t.w;
        W16[2*q+0] = p0;
        W16[2*q+1] = p1;
    }
    const float wih  = W_ih[lane];
    const float bias = b_ih[lane] + b_hh[lane];
    const float fcb0 = fc_b[0], fcb1 = fc_b[1];
    const bool  odd  = (lane & 1) != 0;

    float h = 0.0f;                 // distributed: lane i holds h[i] (fp32)
    float num = 0.0f, den = 0.0f;

    float xv_next = xrow[lane];     // chunk 0's x (one value per lane)

    #pragma unroll 1
    for (int c = 0; c < NCHUNK; ++c) {
        float xcur = xv_next;
        int nidx = (c + 1 < NCHUNK) ? (c + 1) * CHUNK + lane : lane;
        xv_next = xrow[nidx];       // prefetch next chunk's x (off critical path)

        #pragma unroll 8
        for (int r = 0; r < CHUNK; ++r) {
            float xv = bcast_lane(xcur, r);      // x_t, independent of h

            // Pack (h[2k], h[2k+1]) into every lane of pair k via DPP quad-perm
            // neighbor swap [1,0,3,2] = 0xB1 — pure VALU, no LDS.
            int hp_i = __builtin_amdgcn_update_dpp(
                0, __float_as_int(h), 0xB1, 0xF, 0xF, true);
            float hp = __int_as_float(hp_i);
            float lo = odd ? hp : h;
            float hi = odd ? h  : hp;
            h2 hpair; hpair.x = (_Float16)lo; hpair.y = (_Float16)hi;   // RNE
            int hpair_i = h2_as_int(hpair);

            float acc[4];
            acc[0] = fmaf(wih, xv, bias);
            acc[1] = 0.0f; acc[2] = 0.0f; acc[3] = 0.0f;
            #pragma unroll
            for (int k = 0; k < 32; ++k) {
                int pk = __builtin_amdgcn_readlane(hpair_i, 2 * k);  // pair k
                acc[k & 3] = __builtin_amdgcn_fdot2(
                    W16[k], int_as_h2(pk), acc[k & 3], false);
            }
            float a = (acc[0] + acc[1]) + (acc[2] + acc[3]);
            h = tanh_fast(a);
            hbuf[r * ROWSTRIDE + lane] = h;      // fire-and-forget (fp32), fc reads later
        }

        // fc head: lane processes row `lane` -> h_{c*64+lane+1}; over all chunks
        // this consumes exactly h_1..h_8000. Single wave + in-order DS pipe =>
        // writes above are visible, no barrier needed.
        {
            const float4* rp = (const float4*)(hbuf + lane * ROWSTRIDE);
            float d0 = 0.f, d1 = 0.f;
            #pragma unroll
            for (int q = 0; q < 16; ++q) {
                float4 hh = rp[q];
                float4 f0 = ((const float4*)fc_w)[q];          // uniform -> s_load
                float4 f1 = ((const float4*)(fc_w + HID))[q];
                d0 += hh.x * f0.x + hh.y * f0.y + hh.z * f0.z + hh.w * f0.w;
                d1 += hh.x * f1.x + hh.y * f1.y + hh.z * f1.z + hh.w * f1.w;
            }
            float sel = sigmoid_fast(d0 + fcb0);
            float sco = sigmoid_fast(d1 + fcb1);
            num = fmaf(sco, sel, num);
            den += sel;
        }
        // next chunk's ds_writes follow these reads in program order; in-order DS => safe
    }

    // Final cross-lane reduction of (num, den)
    #pragma unroll
    for (int off = 32; off > 0; off >>= 1) {
        num += __shfl_down(num, off);
        den += __shfl_down(den, off);
    }
    if (lane == 0) out[b] = num / den;
}

extern "C" void kernel_launch(void* const* d_in, const int* in_sizes, int n_in,
                              void* d_out, int out_size, void* d_ws, size_t ws_size,
                              hipStream_t stream) {
    const float* x    = (const float*)d_in[0];
    const float* W_ih = (const float*)d_in[1];
    const float* b_ih = (const float*)d_in[2];
    const float* W_hh = (const float*)d_in[3];
    const float* b_hh = (const float*)d_in[4];
    const float* fc_w = (const float*)d_in[5];
    const float* fc_b = (const float*)d_in[6];
    float* out = (float*)d_out;

    rnn_dot2_kernel<<<BATCH, 64, 0, stream>>>(x, W_ih, b_ih, W_hh, b_hh,
                                              fc_w, fc_b, out);
}